// Round 6
// baseline (186.557 us; speedup 1.0000x reference)
//
#include <hip/hip_runtime.h>
#include <hip/hip_fp16.h>

typedef _Float16 f16x8 __attribute__((ext_vector_type(8)));
typedef float    f32x4 __attribute__((ext_vector_type(4)));

#define IMG   512
#define NIMG  64
#define TS_R  32
#define TS_C  64
#define NBLK  (NIMG * (IMG/TS_R) * (IMG/TS_C))   // 8192
#define HST   56     // Ht row stride in halves (112 B: 16B-mult, 2-way-free bank pattern)

#define C1F   1.0e-4f
#define C2F   9.0e-4f

__device__ __forceinline__ uint2 cvt4h(f32x4 a) {
    __half2 p0 = __floats2half2_rn(a[0], a[1]);
    __half2 p1 = __floats2half2_rn(a[2], a[3]);
    uint2 r; r.x = *reinterpret_cast<uint*>(&p0); r.y = *reinterpret_cast<uint*>(&p1);
    return r;
}

__device__ __forceinline__ f16x8 to8(float4 a, float4 b) {
    f16x8 r;
    r[0]=(_Float16)a.x; r[1]=(_Float16)a.y; r[2]=(_Float16)a.z; r[3]=(_Float16)a.w;
    r[4]=(_Float16)b.x; r[5]=(_Float16)b.y; r[6]=(_Float16)b.z; r[7]=(_Float16)b.w;
    return r;
}

__global__ __launch_bounds__(256, 4)
void ssim_main(const float* __restrict__ x, const float* __restrict__ y,
               float* __restrict__ partial) {
    // Ht[field][tile_col][h_row] fp16 — the only LDS use. 5*64*56*2 = 35840 B.
    __shared__ __align__(16) __half Ht[5][TS_C][HST];
    __shared__ float red[4];

    const int tid  = threadIdx.x;
    const int lane = tid & 63;
    const int wv   = tid >> 6;       // wave 0..3 -> 16-col output strip
    const int l16  = lane & 15;
    const int g16  = lane >> 4;
    const int n0   = wv * 16;

    const int img = blockIdx.z;
    const int r0  = blockIdx.y * TS_R;
    const int c0  = blockIdx.x * TS_C;
    const float* xb = x + (size_t)img * IMG * IMG;
    const float* yb = y + (size_t)img * IMG * IMG;

    const int hcol = n0 + l16;                // this lane's tile column
    const int wc   = c0 + n0 - 8 + g16 * 8;   // K-window col base for this lane
    const bool okA = (unsigned)wc       <= 508u;   // float4 fully in [0,512)
    const bool okB = (unsigned)(wc + 4) <= 508u;
    const float4 z4 = make_float4(0.f, 0.f, 0.f, 0.f);

    // ---- Issue ALL global loads up front (12x dwordx4 per thread, max MLP) ----
    float4 Xa[3], Xb_[3], Ya[3], Yb[3];
    #pragma unroll
    for (int mg = 0; mg < 3; ++mg) {
        int  hr  = r0 + mg * 16 + l16 - 5;     // image row for H-row mg*16+l16
        bool rok = (unsigned)hr < (unsigned)IMG;
        const float* xr = xb + (size_t)hr * IMG + wc;
        const float* yr = yb + (size_t)hr * IMG + wc;
        Xa[mg]  = (rok && okA) ? *(const float4*)(xr)     : z4;
        Xb_[mg] = (rok && okB) ? *(const float4*)(xr + 4) : z4;
        Ya[mg]  = (rok && okA) ? *(const float4*)(yr)     : z4;
        Yb[mg]  = (rok && okB) ? *(const float4*)(yr + 4) : z4;
    }

    // ---- Band fragments (overlaps with loads in flight) ----
    float wsum = 0.0f;
    #pragma unroll
    for (int k = 0; k < 11; ++k) {
        float d = (float)(k - 5);
        wsum += __expf(-d * d * (1.0f / 4.5f));
    }
    const float inv = 1.0f / wsum;

    //  H-pass B[k][n] = w(k - n - 3), k=g16*8+j, n=l16  -> d = d0 + j
    //  V-pass A[r][k] = w(k - r),     r=l16, k=g16*8+j  -> d = d0 + j + 3
    const int d0 = g16 * 8 - l16 - 3;
    _Float16 bv[11];
    #pragma unroll
    for (int j = 0; j < 11; ++j) {
        int d = d0 + j;
        float t = (float)(d - 5);
        float v = __expf(-t * t * (1.0f / 4.5f)) * inv;
        bv[j] = ((unsigned)d <= 10u) ? (_Float16)v : (_Float16)0.0f;
    }
    f16x8 WhB, WvA;
    #pragma unroll
    for (int j = 0; j < 8; ++j) WhB[j] = bv[j];
    #pragma unroll
    for (int j = 0; j < 8; ++j) WvA[j] = bv[j + 3];

    // ---- H pass: 3 row-groups of 16 H-rows; A = loaded rows, B = band ----
    #pragma unroll
    for (int mg = 0; mg < 3; ++mg) {
        f16x8 xf = to8(Xa[mg], Xb_[mg]);
        f16x8 yf = to8(Ya[mg], Yb[mg]);
        f16x8 xx = xf * xf;
        f16x8 yy = yf * yf;
        f16x8 xy = xf * yf;
        f32x4 z = {0.f, 0.f, 0.f, 0.f};
        f32x4 aX  = __builtin_amdgcn_mfma_f32_16x16x32_f16(xf, WhB, z, 0, 0, 0);
        f32x4 aY  = __builtin_amdgcn_mfma_f32_16x16x32_f16(yf, WhB, z, 0, 0, 0);
        f32x4 aXX = __builtin_amdgcn_mfma_f32_16x16x32_f16(xx, WhB, z, 0, 0, 0);
        f32x4 aYY = __builtin_amdgcn_mfma_f32_16x16x32_f16(yy, WhB, z, 0, 0, 0);
        f32x4 aXY = __builtin_amdgcn_mfma_f32_16x16x32_f16(xy, WhB, z, 0, 0, 0);
        // C layout: col = lane&15 (= output col l16), rows = mg*16 + g16*4 + r.
        int hrow = mg * 16 + g16 * 4;
        *(uint2*)&Ht[0][hcol][hrow] = cvt4h(aX);
        *(uint2*)&Ht[1][hcol][hrow] = cvt4h(aY);
        *(uint2*)&Ht[2][hcol][hrow] = cvt4h(aXX);
        *(uint2*)&Ht[3][hcol][hrow] = cvt4h(aYY);
        *(uint2*)&Ht[4][hcol][hrow] = cvt4h(aXY);
    }
    // No barrier: each wave's V-pass reads only its own 16-col Ht strip.

    // ---- V pass: issue all 10 b128 reads, then MFMAs, then epilogue ----
    f16x8 bf[2][5];
    #pragma unroll
    for (int mt = 0; mt < 2; ++mt) {
        int ko = mt * 16 + g16 * 8;
        #pragma unroll
        for (int f = 0; f < 5; ++f)
            bf[mt][f] = *(const f16x8*)&Ht[f][hcol][ko];
    }

    float ssum = 0.0f;
    #pragma unroll
    for (int mt = 0; mt < 2; ++mt) {
        f32x4 z = {0.f, 0.f, 0.f, 0.f};
        f32x4 cX  = __builtin_amdgcn_mfma_f32_16x16x32_f16(WvA, bf[mt][0], z, 0, 0, 0);
        f32x4 cY  = __builtin_amdgcn_mfma_f32_16x16x32_f16(WvA, bf[mt][1], z, 0, 0, 0);
        f32x4 cXX = __builtin_amdgcn_mfma_f32_16x16x32_f16(WvA, bf[mt][2], z, 0, 0, 0);
        f32x4 cYY = __builtin_amdgcn_mfma_f32_16x16x32_f16(WvA, bf[mt][3], z, 0, 0, 0);
        f32x4 cXY = __builtin_amdgcn_mfma_f32_16x16x32_f16(WvA, bf[mt][4], z, 0, 0, 0);
        #pragma unroll
        for (int r = 0; r < 4; ++r) {
            float mx  = cX[r];
            float my  = cY[r];
            float exx = cXX[r];
            float eyy = cYY[r];
            float exy = cXY[r];
            float mxx = mx * mx, myy = my * my, mxy = mx * my;
            float vx  = exx - mxx;
            float vy  = eyy - myy;
            float vxy = exy - mxy;
            float num = (2.0f * mxy + C1F) * (2.0f * vxy + C2F);
            float den = (mxx + myy + C1F) * (vx + vy + C2F);
            ssum = fmaf(num, __builtin_amdgcn_rcpf(den), ssum);
        }
    }

    // ---- Block reduction (deterministic) ----
    #pragma unroll
    for (int off = 32; off > 0; off >>= 1)
        ssum += __shfl_down(ssum, off, 64);
    if ((tid & 63) == 0) red[tid >> 6] = ssum;
    __syncthreads();
    if (tid == 0) {
        float tot = red[0] + red[1] + red[2] + red[3];
        int bi = (blockIdx.z * gridDim.y + blockIdx.y) * gridDim.x + blockIdx.x;
        partial[bi] = tot;
    }
}

__global__ __launch_bounds__(1024)
void ssim_final(const float* __restrict__ partial, float* __restrict__ out) {
    __shared__ float red[16];
    float s = 0.0f;
    for (int i = threadIdx.x; i < NBLK; i += 1024) s += partial[i];
    #pragma unroll
    for (int off = 32; off > 0; off >>= 1)
        s += __shfl_down(s, off, 64);
    if ((threadIdx.x & 63) == 0) red[threadIdx.x >> 6] = s;
    __syncthreads();
    if (threadIdx.x == 0) {
        float tot = 0.0f;
        #pragma unroll
        for (int i = 0; i < 16; ++i) tot += red[i];
        out[0] = 1.0f - tot * (1.0f / 16777216.0f);
    }
}

extern "C" void kernel_launch(void* const* d_in, const int* in_sizes, int n_in,
                              void* d_out, int out_size, void* d_ws, size_t ws_size,
                              hipStream_t stream) {
    const float* x = (const float*)d_in[0];
    const float* y = (const float*)d_in[1];
    float* out     = (float*)d_out;
    float* partial = (float*)d_ws;   // NBLK floats = 32 KB

    dim3 grid(IMG / TS_C, IMG / TS_R, NIMG);   // (8, 16, 64)
    ssim_main<<<grid, 256, 0, stream>>>(x, y, partial);
    ssim_final<<<1, 1024, 0, stream>>>(partial, out);
}

// Round 9
// 66.445 us; speedup vs baseline: 2.8077x; 2.8077x over previous
//
#include <hip/hip_runtime.h>
#include <hip/hip_fp16.h>

typedef _Float16 f16x8 __attribute__((ext_vector_type(8)));
typedef float    f32x4 __attribute__((ext_vector_type(4)));

#define IMG   512
#define NIMG  64
#define TS_R  32
#define TS_C  64
#define NBLK  (NIMG * (IMG/TS_R) * (IMG/TS_C))   // 8192
#define XST   88     // staged row stride in halves (176 B: 16B-mult, <=2-way banks)
#define HST   56     // Ht row stride in halves   (112 B: 16B-mult)
#define SROWS 42     // staged rows (image rows r0-5 .. r0+36)
#define SCOLS 80     // staged cols (tile cols c0-8 .. c0+71)
#define NU    840    // float4 units per plane = 42 * (80/4)

#define C1F   1.0e-4f
#define C2F   9.0e-4f

__device__ __forceinline__ uint2 cvt4h(f32x4 a) {
    __half2 p0 = __floats2half2_rn(a[0], a[1]);
    __half2 p1 = __floats2half2_rn(a[2], a[3]);
    uint2 r; r.x = *reinterpret_cast<uint*>(&p0); r.y = *reinterpret_cast<uint*>(&p1);
    return r;
}

__global__ __launch_bounds__(256, 3)
void ssim_main(const float* __restrict__ x, const float* __restrict__ y,
               float* __restrict__ partial) {
    // Single staging array: plane 0 = X, plane 1 = Y.
    __shared__ __align__(16) __half XYp[2 * SROWS * XST];   // 14784 B
    __shared__ __align__(16) __half Ht[5][TS_C][HST];       // 35840 B
    __shared__ float red[4];

    const int tid  = threadIdx.x;
    const int lane = tid & 63;
    const int wv   = tid >> 6;       // wave 0..3 -> 16-col output strip
    const int l16  = lane & 15;
    const int g16  = lane >> 4;
    const int n0   = wv * 16;

    const int img = blockIdx.z;
    const int r0  = blockIdx.y * TS_R;
    const int c0  = blockIdx.x * TS_C;
    const float* xb = x + (size_t)img * IMG * IMG;
    const float* yb = y + (size_t)img * IMG * IMG;

    // ---- Coalesced staging: 2*840 float4 units, ~7 independent loads/thread ----
    float4 st[7];
    int    dst_[7];
    bool   vld_[7];
    #pragma unroll
    for (int i = 0; i < 7; ++i) {
        int  u     = tid + i * 256;
        bool valid = (u < 2 * NU);
        int  uu    = valid ? u : 0;
        bool ya    = uu >= NU;
        int  e     = ya ? uu - NU : uu;
        int  row   = e / (SCOLS / 4);
        int  c4    = e - row * (SCOLS / 4);
        int  j0    = c4 * 4;
        int  gr    = r0 - 5 + row;
        int  gc    = c0 - 8 + j0;           // float4 never straddles [0,512) edges
        bool ok    = valid & ((unsigned)gr < (unsigned)IMG) & ((unsigned)gc < (unsigned)IMG);
        const float* src = (ya ? yb : xb) + (size_t)gr * IMG + gc;
        st[i]   = ok ? *(const float4*)src : make_float4(0.f, 0.f, 0.f, 0.f);
        dst_[i] = (ya ? SROWS * XST : 0) + row * XST + j0;
        vld_[i] = valid;
    }

    // ---- Band fragments (VALU-only, overlaps with loads in flight) ----
    float wsum = 0.0f;
    #pragma unroll
    for (int k = 0; k < 11; ++k) {
        float d = (float)(k - 5);
        wsum += __expf(-d * d * (1.0f / 4.5f));
    }
    const float inv = 1.0f / wsum;

    //  H-pass B[k][n] = w(k - n - 3), k=g16*8+j, n=l16  -> d = d0 + j
    //  V-pass A[r][k] = w(k - r),     r=l16, k=g16*8+j  -> d = d0 + j + 3
    const int d0 = g16 * 8 - l16 - 3;
    _Float16 bv[11];
    #pragma unroll
    for (int j = 0; j < 11; ++j) {
        int d = d0 + j;
        float t = (float)(d - 5);
        float v = __expf(-t * t * (1.0f / 4.5f)) * inv;
        bv[j] = ((unsigned)d <= 10u) ? (_Float16)v : (_Float16)0.0f;
    }
    f16x8 WhB, WvA;
    #pragma unroll
    for (int j = 0; j < 8; ++j) WhB[j] = bv[j];
    #pragma unroll
    for (int j = 0; j < 8; ++j) WvA[j] = bv[j + 3];

    // ---- Write staged data to LDS as fp16 ----
    #pragma unroll
    for (int i = 0; i < 7; ++i) {
        if (vld_[i]) {
            __half2 p0 = __floats2half2_rn(st[i].x, st[i].y);
            __half2 p1 = __floats2half2_rn(st[i].z, st[i].w);
            uint2 v; v.x = *reinterpret_cast<uint*>(&p0); v.y = *reinterpret_cast<uint*>(&p1);
            *(uint2*)&XYp[dst_[i]] = v;
        }
    }
    __syncthreads();

    // ---- H pass: 3 row-groups; A = staged rows (ds_read_b128), B = band ----
    // H-rows 42..47 (mg=2, l16>=10) are consumed ONLY with w=0 in the V-pass
    // (k-r >= 11 for all output rows), so clamp their staged-row index to 41:
    // values are duplicates of row 41 — finite, zero-weighted, in-bounds.
    const int hcol = n0 + l16;
    #pragma unroll
    for (int mg = 0; mg < 3; ++mg) {
        int srow = mg * 16 + l16;
        if (srow > SROWS - 1) srow = SROWS - 1;
        int off = srow * XST + n0 + g16 * 8;
        f16x8 xf = *(const f16x8*)&XYp[off];
        f16x8 yf = *(const f16x8*)&XYp[SROWS * XST + off];
        f16x8 xx = xf * xf;
        f16x8 yy = yf * yf;
        f16x8 xy = xf * yf;
        f32x4 z = {0.f, 0.f, 0.f, 0.f};
        f32x4 aX  = __builtin_amdgcn_mfma_f32_16x16x32_f16(xf, WhB, z, 0, 0, 0);
        f32x4 aY  = __builtin_amdgcn_mfma_f32_16x16x32_f16(yf, WhB, z, 0, 0, 0);
        f32x4 aXX = __builtin_amdgcn_mfma_f32_16x16x32_f16(xx, WhB, z, 0, 0, 0);
        f32x4 aYY = __builtin_amdgcn_mfma_f32_16x16x32_f16(yy, WhB, z, 0, 0, 0);
        f32x4 aXY = __builtin_amdgcn_mfma_f32_16x16x32_f16(xy, WhB, z, 0, 0, 0);
        // C layout: col = lane&15 (= output col l16), rows = mg*16 + g16*4 + r.
        int hrow = mg * 16 + g16 * 4;
        *(uint2*)&Ht[0][hcol][hrow] = cvt4h(aX);
        *(uint2*)&Ht[1][hcol][hrow] = cvt4h(aY);
        *(uint2*)&Ht[2][hcol][hrow] = cvt4h(aXX);
        *(uint2*)&Ht[3][hcol][hrow] = cvt4h(aYY);
        *(uint2*)&Ht[4][hcol][hrow] = cvt4h(aXY);
    }
    // No barrier: each wave's V-pass reads only its own 16-col Ht strip.

    // ---- V pass: issue all 10 b128 reads, then MFMAs, then epilogue ----
    f16x8 bf[2][5];
    #pragma unroll
    for (int mt = 0; mt < 2; ++mt) {
        int ko = mt * 16 + g16 * 8;
        #pragma unroll
        for (int f = 0; f < 5; ++f)
            bf[mt][f] = *(const f16x8*)&Ht[f][hcol][ko];
    }

    float ssum = 0.0f;
    #pragma unroll
    for (int mt = 0; mt < 2; ++mt) {
        f32x4 z = {0.f, 0.f, 0.f, 0.f};
        f32x4 cX  = __builtin_amdgcn_mfma_f32_16x16x32_f16(WvA, bf[mt][0], z, 0, 0, 0);
        f32x4 cY  = __builtin_amdgcn_mfma_f32_16x16x32_f16(WvA, bf[mt][1], z, 0, 0, 0);
        f32x4 cXX = __builtin_amdgcn_mfma_f32_16x16x32_f16(WvA, bf[mt][2], z, 0, 0, 0);
        f32x4 cYY = __builtin_amdgcn_mfma_f32_16x16x32_f16(WvA, bf[mt][3], z, 0, 0, 0);
        f32x4 cXY = __builtin_amdgcn_mfma_f32_16x16x32_f16(WvA, bf[mt][4], z, 0, 0, 0);
        #pragma unroll
        for (int r = 0; r < 4; ++r) {
            float mx  = cX[r];
            float my  = cY[r];
            float exx = cXX[r];
            float eyy = cYY[r];
            float exy = cXY[r];
            float mxx = mx * mx, myy = my * my, mxy = mx * my;
            float vx  = exx - mxx;
            float vy  = eyy - myy;
            float vxy = exy - mxy;
            float num = (2.0f * mxy + C1F) * (2.0f * vxy + C2F);
            float den = (mxx + myy + C1F) * (vx + vy + C2F);
            ssum = fmaf(num, __builtin_amdgcn_rcpf(den), ssum);
        }
    }

    // ---- Block reduction (deterministic) ----
    #pragma unroll
    for (int off = 32; off > 0; off >>= 1)
        ssum += __shfl_down(ssum, off, 64);
    if ((tid & 63) == 0) red[tid >> 6] = ssum;
    __syncthreads();
    if (tid == 0) {
        float tot = red[0] + red[1] + red[2] + red[3];
        int bi = (blockIdx.z * gridDim.y + blockIdx.y) * gridDim.x + blockIdx.x;
        partial[bi] = tot;
    }
}

__global__ __launch_bounds__(1024)
void ssim_final(const float* __restrict__ partial, float* __restrict__ out) {
    __shared__ float red[16];
    float s = 0.0f;
    for (int i = threadIdx.x; i < NBLK; i += 1024) s += partial[i];
    #pragma unroll
    for (int off = 32; off > 0; off >>= 1)
        s += __shfl_down(s, off, 64);
    if ((threadIdx.x & 63) == 0) red[threadIdx.x >> 6] = s;
    __syncthreads();
    if (threadIdx.x == 0) {
        float tot = 0.0f;
        #pragma unroll
        for (int i = 0; i < 16; ++i) tot += red[i];
        out[0] = 1.0f - tot * (1.0f / 16777216.0f);
    }
}

extern "C" void kernel_launch(void* const* d_in, const int* in_sizes, int n_in,
                              void* d_out, int out_size, void* d_ws, size_t ws_size,
                              hipStream_t stream) {
    const float* x = (const float*)d_in[0];
    const float* y = (const float*)d_in[1];
    float* out     = (float*)d_out;
    float* partial = (float*)d_ws;   // NBLK floats = 32 KB

    dim3 grid(IMG / TS_C, IMG / TS_R, NIMG);   // (8, 16, 64)
    ssim_main<<<grid, 256, 0, stream>>>(x, y, partial);
    ssim_final<<<1, 1024, 0, stream>>>(partial, out);
}

// Round 10
// 55.617 us; speedup vs baseline: 3.3543x; 1.1947x over previous
//
#include <hip/hip_runtime.h>
#include <hip/hip_fp16.h>

typedef _Float16 f16x8 __attribute__((ext_vector_type(8)));
typedef float    f32x4 __attribute__((ext_vector_type(4)));

#define IMG   512
#define NIMG  64
#define TS_R  32
#define TS_C  64
#define NBLK  (NIMG * (IMG/TS_R) * (IMG/TS_C))   // 8192
#define XST   88     // staged row stride in halves (176 B: 16B-mult, 2-way banks)
#define HTS   40     // Ht slot stride in halves (80 B: 16B-mult, 2-way banks), 32 slots
#define SROWS 42     // staged rows per plane (image rows r0-5 .. r0+36)
#define NU    840    // float4 units per plane = 42 * 20

#define C1F   1.0e-4f
#define C2F   9.0e-4f
#define INVSUM 0.26601174f   // 1 / sum_{k=0..10} exp(-(k-5)^2/4.5), precomputed

__device__ __forceinline__ uint2 cvt4h(f32x4 a) {
    __half2 p0 = __floats2half2_rn(a[0], a[1]);
    __half2 p1 = __floats2half2_rn(a[2], a[3]);
    uint2 r; r.x = *reinterpret_cast<uint*>(&p0); r.y = *reinterpret_cast<uint*>(&p1);
    return r;
}

__global__ __launch_bounds__(256, 4)
void ssim_main(const float* __restrict__ x, const float* __restrict__ y,
               float* __restrict__ partial) {
    // Plane 0 = X (rows 0..41), plane 1 = Y (rows 42..83) — one contiguous array.
    __shared__ __align__(16) __half XYp[2 * SROWS * XST];   // 14784 B
    // Ring-buffered H fields: 32 slots (slot = h_row & 31).
    __shared__ __align__(16) __half Ht[5][TS_C][HTS];       // 25600 B
    __shared__ float red[4];

    const int tid  = threadIdx.x;
    const int lane = tid & 63;
    const int wv   = tid >> 6;       // wave 0..3 -> 16-col output strip
    const int l16  = lane & 15;
    const int g16  = lane >> 4;
    const int n0   = wv * 16;

    const int img = blockIdx.z;
    const int r0  = blockIdx.y * TS_R;
    const int c0  = blockIdx.x * TS_C;
    const float* xb = x + (size_t)img * IMG * IMG;
    const float* yb = y + (size_t)img * IMG * IMG;

    // ---- Coalesced staging: 1680 float4 units over 7x256; one div, then walk ----
    float4 st[7];
    int    dst_[7];
    {
        int row_u = tid / 20;            // combined row index 0..83 (X rows, then Y)
        int c4    = tid - row_u * 20;    // float4-unit col 0..19
        #pragma unroll
        for (int i = 0; i < 7; ++i) {
            bool valid = (i < 6) | (tid < 144);        // u = tid+1536 < 1680
            bool ya  = row_u >= SROWS;
            int  rp  = ya ? row_u - SROWS : row_u;
            int  gr  = r0 - 5 + rp;
            int  gc  = c0 - 8 + c4 * 4;                // never straddles [0,512)
            bool ok  = valid & ((unsigned)gr < (unsigned)IMG) & ((unsigned)gc < (unsigned)IMG);
            const float* src = (ya ? yb : xb) + (size_t)gr * IMG + gc;
            st[i]   = ok ? *(const float4*)src : make_float4(0.f, 0.f, 0.f, 0.f);
            dst_[i] = row_u * XST + c4 * 4;            // plane-free (42*XST offset implicit)
            // advance by 256 units = 12 rows + 16 units
            c4 += 16;
            int inc = 12;
            if (c4 >= 20) { c4 -= 20; inc = 13; }
            row_u += inc;
        }
    }

    // ---- Band fragments (VALU-only, overlaps with loads in flight) ----
    //  H-pass B[k][n] = w(k - n - 3), k=g16*8+j, n=l16  -> d = d0 + j
    //  V-pass A[r][k] = w(k - r),     r=l16, k=g16*8+j  -> d = d0 + j + 3
    const int d0 = g16 * 8 - l16 - 3;
    _Float16 bv[11];
    #pragma unroll
    for (int j = 0; j < 11; ++j) {
        int d = d0 + j;
        float t = (float)(d - 5);
        float v = __expf(-t * t * (1.0f / 4.5f)) * INVSUM;
        bv[j] = ((unsigned)d <= 10u) ? (_Float16)v : (_Float16)0.0f;
    }
    f16x8 WhB, WvA;
    #pragma unroll
    for (int j = 0; j < 8; ++j) WhB[j] = bv[j];
    #pragma unroll
    for (int j = 0; j < 8; ++j) WvA[j] = bv[j + 3];

    // ---- Write staged data to LDS as fp16 ----
    #pragma unroll
    for (int i = 0; i < 7; ++i) {
        if (i < 6 || tid < 144) {
            __half2 p0 = __floats2half2_rn(st[i].x, st[i].y);
            __half2 p1 = __floats2half2_rn(st[i].z, st[i].w);
            uint2 v; v.x = *reinterpret_cast<uint*>(&p0); v.y = *reinterpret_cast<uint*>(&p1);
            *(uint2*)&XYp[dst_[i]] = v;
        }
    }
    __syncthreads();

    const int hcol = n0 + l16;
    float ssum = 0.0f;

    // H pass for one 16-row group of h-rows [mg*16, mg*16+16); writes slot base sb.
    // H-rows 42..47 are zero-weighted in the V-pass -> clamp staged row to 41.
    auto hpass = [&](int mg, int sb) {
        int srow = mg * 16 + l16;
        if (srow > SROWS - 1) srow = SROWS - 1;
        int off = srow * XST + n0 + g16 * 8;
        f16x8 xf = *(const f16x8*)&XYp[off];
        f16x8 yf = *(const f16x8*)&XYp[SROWS * XST + off];
        f16x8 xx = xf * xf;
        f16x8 yy = yf * yf;
        f16x8 xy = xf * yf;
        f32x4 z = {0.f, 0.f, 0.f, 0.f};
        f32x4 aX  = __builtin_amdgcn_mfma_f32_16x16x32_f16(xf, WhB, z, 0, 0, 0);
        f32x4 aY  = __builtin_amdgcn_mfma_f32_16x16x32_f16(yf, WhB, z, 0, 0, 0);
        f32x4 aXX = __builtin_amdgcn_mfma_f32_16x16x32_f16(xx, WhB, z, 0, 0, 0);
        f32x4 aYY = __builtin_amdgcn_mfma_f32_16x16x32_f16(yy, WhB, z, 0, 0, 0);
        f32x4 aXY = __builtin_amdgcn_mfma_f32_16x16x32_f16(xy, WhB, z, 0, 0, 0);
        int hrow = sb + g16 * 4;     // slot; C layout: col=l16, rows=g16*4+reg
        *(uint2*)&Ht[0][hcol][hrow] = cvt4h(aX);
        *(uint2*)&Ht[1][hcol][hrow] = cvt4h(aY);
        *(uint2*)&Ht[2][hcol][hrow] = cvt4h(aXX);
        *(uint2*)&Ht[3][hcol][hrow] = cvt4h(aYY);
        *(uint2*)&Ht[4][hcol][hrow] = cvt4h(aXY);
    };

    // V pass over h-row window [mt*16, mt*16+32): slots (mt*16 + g16*8) & 31.
    auto vpass = [&](int mt) {
        int ko = (mt * 16 + g16 * 8) & 31;   // 8-slot groups never straddle the wrap
        f16x8 b0 = *(const f16x8*)&Ht[0][hcol][ko];
        f16x8 b1 = *(const f16x8*)&Ht[1][hcol][ko];
        f16x8 b2 = *(const f16x8*)&Ht[2][hcol][ko];
        f16x8 b3 = *(const f16x8*)&Ht[3][hcol][ko];
        f16x8 b4 = *(const f16x8*)&Ht[4][hcol][ko];
        f32x4 z = {0.f, 0.f, 0.f, 0.f};
        f32x4 cX  = __builtin_amdgcn_mfma_f32_16x16x32_f16(WvA, b0, z, 0, 0, 0);
        f32x4 cY  = __builtin_amdgcn_mfma_f32_16x16x32_f16(WvA, b1, z, 0, 0, 0);
        f32x4 cXX = __builtin_amdgcn_mfma_f32_16x16x32_f16(WvA, b2, z, 0, 0, 0);
        f32x4 cYY = __builtin_amdgcn_mfma_f32_16x16x32_f16(WvA, b3, z, 0, 0, 0);
        f32x4 cXY = __builtin_amdgcn_mfma_f32_16x16x32_f16(WvA, b4, z, 0, 0, 0);
        #pragma unroll
        for (int r = 0; r < 4; ++r) {
            float mx  = cX[r];
            float my  = cY[r];
            float exx = cXX[r];
            float eyy = cYY[r];
            float exy = cXY[r];
            float mxx = mx * mx, myy = my * my, mxy = mx * my;
            float vx  = exx - mxx;
            float vy  = eyy - myy;
            float vxy = exy - mxy;
            float num = (2.0f * mxy + C1F) * (2.0f * vxy + C2F);
            float den = (mxx + myy + C1F) * (vx + vy + C2F);
            ssum = fmaf(num, __builtin_amdgcn_rcpf(den), ssum);
        }
    };

    // Ring schedule (wave-private columns -> no barriers; same-wave LDS is in-order):
    hpass(0, 0);      // h 0..15  -> slots 0..15
    hpass(1, 16);     // h 16..31 -> slots 16..31
    vpass(0);         // reads slots 0..31 (h 0..31)
    hpass(2, 0);      // h 32..47 -> slots 0..15 (after vpass(0) read them)
    vpass(1);         // reads h 16..47 = slots 16..31, 0..15

    // ---- Block reduction (deterministic) ----
    #pragma unroll
    for (int off = 32; off > 0; off >>= 1)
        ssum += __shfl_down(ssum, off, 64);
    if ((tid & 63) == 0) red[tid >> 6] = ssum;
    __syncthreads();
    if (tid == 0) {
        float tot = red[0] + red[1] + red[2] + red[3];
        int bi = (blockIdx.z * gridDim.y + blockIdx.y) * gridDim.x + blockIdx.x;
        partial[bi] = tot;
    }
}

__global__ __launch_bounds__(1024)
void ssim_final(const float* __restrict__ partial, float* __restrict__ out) {
    __shared__ float red[16];
    float s = 0.0f;
    for (int i = threadIdx.x; i < NBLK; i += 1024) s += partial[i];
    #pragma unroll
    for (int off = 32; off > 0; off >>= 1)
        s += __shfl_down(s, off, 64);
    if ((threadIdx.x & 63) == 0) red[threadIdx.x >> 6] = s;
    __syncthreads();
    if (threadIdx.x == 0) {
        float tot = 0.0f;
        #pragma unroll
        for (int i = 0; i < 16; ++i) tot += red[i];
        out[0] = 1.0f - tot * (1.0f / 16777216.0f);
    }
}

extern "C" void kernel_launch(void* const* d_in, const int* in_sizes, int n_in,
                              void* d_out, int out_size, void* d_ws, size_t ws_size,
                              hipStream_t stream) {
    const float* x = (const float*)d_in[0];
    const float* y = (const float*)d_in[1];
    float* out     = (float*)d_out;
    float* partial = (float*)d_ws;   // NBLK floats = 32 KB

    dim3 grid(IMG / TS_C, IMG / TS_R, NIMG);   // (8, 16, 64)
    ssim_main<<<grid, 256, 0, stream>>>(x, y, partial);
    ssim_final<<<1, 1024, 0, stream>>>(partial, out);
}